// Round 1
// baseline (596.464 us; speedup 1.0000x reference)
//
#include <hip/hip_runtime.h>

#define B_   4
#define CV_  64
#define CI_  256
#define HF_  48
#define WF_  160
#define PLANE_ (HF_*WF_)          // 7680
#define IMG_B_ (CI_*PLANE_)       // 1966080

// One block (320 threads) per point.
//  t in [0,64)  : copy voxel_feats[n, t]  -> out[n, t]
//  t in [64,320): c = t-64; bilinear-gather img_feats[b, c, ., .] -> out[n, 64+c]
__global__ __launch_bounds__(320) void i2p_kernel(
    const float* __restrict__ points_mean,  // (N,1,3)
    const float* __restrict__ voxel_feats,  // (N,64)
    const int*   __restrict__ coors,        // (N,4)
    const float* __restrict__ img_feats,    // (B,256,48,160)
    const float* __restrict__ lidar2img,    // (B,4,4)
    const int*   __restrict__ pad_shape,    // (B,2)
    float*       __restrict__ out,          // (N,320)
    int N)
{
    __shared__ float sw[4];
    __shared__ int   sb[4];

    const int n = blockIdx.x;
    if (n >= N) return;
    const int t = threadIdx.x;

    if (t == 0) {
        const int b = coors[n * 4];
        const float px = points_mean[n * 3 + 0];
        const float py = points_mean[n * 3 + 1];
        const float pz = points_mean[n * 3 + 2];
        const float* M = lidar2img + b * 16;
        const float ip0 = M[0]*px + M[1]*py + M[2]*pz  + M[3];
        const float ip1 = M[4]*px + M[5]*py + M[6]*pz  + M[7];
        const float ip2 = M[8]*px + M[9]*py + M[10]*pz + M[11];
        const float z  = fmaxf(ip2, 1e-5f);
        const float x_pix = ip0 / z;
        const float y_pix = ip1 / z;
        const float hw0 = (float)pad_shape[b * 2 + 0];   // PAD_H
        const float hw1 = (float)pad_shape[b * 2 + 1];   // PAD_W
        const float gx = x_pix / hw1 * 2.0f - 1.0f;
        const float gy = y_pix / hw0 * 2.0f - 1.0f;
        const float ix = (gx + 1.0f) * 0.5f * (float)(WF_ - 1);
        const float iy = (gy + 1.0f) * 0.5f * (float)(HF_ - 1);
        const float ix0 = floorf(ix);
        const float iy0 = floorf(iy);
        const float wx1 = ix - ix0, wx0 = 1.0f - wx1;
        const float wy1 = iy - iy0, wy0 = 1.0f - wy1;

        const float xs[2]  = {ix0, ix0 + 1.0f};
        const float ys[2]  = {iy0, iy0 + 1.0f};
        const float wxs[2] = {wx0, wx1};
        const float wys[2] = {wy0, wy1};
        const int   ib = b * IMG_B_;

        #pragma unroll
        for (int ky = 0; ky < 2; ++ky) {
            #pragma unroll
            for (int kx = 0; kx < 2; ++kx) {
                const int k = ky * 2 + kx;
                // validity checked on the FLOAT side (floor values are exact
                // integers in range, and this avoids out-of-range f->i UB)
                const bool valid =
                    (ys[ky] >= 0.0f) && (ys[ky] <= (float)(HF_ - 1)) &&
                    (xs[kx] >= 0.0f) && (xs[kx] <= (float)(WF_ - 1));
                if (valid) {
                    const int yc = (int)ys[ky];
                    const int xc = (int)xs[kx];
                    sb[k] = ib + yc * WF_ + xc;
                    sw[k] = wys[ky] * wxs[kx];
                } else {
                    sb[k] = 0;
                    sw[k] = 0.0f;
                }
            }
        }
    }
    __syncthreads();

    const long o = (long)n * 320 + t;
    if (t < 64) {
        out[o] = voxel_feats[(long)n * 64 + t];
    } else {
        const int c = t - 64;
        const int coff = c * PLANE_;
        float acc = 0.0f;
        #pragma unroll
        for (int k = 0; k < 4; ++k) {
            const float w = sw[k];             // wave-uniform -> no divergence
            if (w != 0.0f)
                acc += w * img_feats[sb[k] + coff];
        }
        out[o] = acc;
    }
}

extern "C" void kernel_launch(void* const* d_in, const int* in_sizes, int n_in,
                              void* d_out, int out_size, void* d_ws, size_t ws_size,
                              hipStream_t stream) {
    const float* points_mean = (const float*)d_in[0];
    // d_in[1] = mask (unused by forward)
    const float* voxel_feats = (const float*)d_in[2];
    const int*   coors       = (const int*)d_in[3];
    const float* img_feats   = (const float*)d_in[4];
    const float* lidar2img   = (const float*)d_in[5];
    const int*   pad_shape   = (const int*)d_in[6];
    float*       out         = (float*)d_out;

    const int N = in_sizes[0] / 3;   // points_mean is (N,1,3)

    dim3 grid(N);
    dim3 block(320);
    hipLaunchKernelGGL(i2p_kernel, grid, block, 0, stream,
                       points_mean, voxel_feats, coors, img_feats,
                       lidar2img, pad_shape, out, N);
}

// Round 2
// 375.831 us; speedup vs baseline: 1.5871x; 1.5871x over previous
//
#include <hip/hip_runtime.h>

#define B_   4
#define CV_  64
#define CI_  256
#define HF_  48
#define WF_  160
#define PLANE_ (HF_*WF_)            // 7680
#define IMG_B_ (CI_*PLANE_)         // 1966080 floats per batch
#define IMG_BYTES_ ((size_t)B_ * IMG_B_ * 4)   // 31,457,280 B

// ---------------------------------------------------------------------------
// Pre-pass: transpose img_feats (B, C, H*W) -> img_t (B, H*W, C)
// Classic LDS-tiled 32x32 transpose; both global read and write coalesced.
// ---------------------------------------------------------------------------
__global__ __launch_bounds__(256) void transpose_kernel(
    const float* __restrict__ in,    // (B, C, P)
    float*       __restrict__ outp)  // (B, P, C)
{
    __shared__ float tile[32][33];   // +1 pad: no bank conflicts
    const int b  = blockIdx.z;
    const int p0 = blockIdx.x * 32;  // pixel tile
    const int c0 = blockIdx.y * 32;  // channel tile
    const int tx = threadIdx.x & 31;
    const int ty = threadIdx.x >> 5; // 0..7

    const float* ib = in   + (size_t)b * IMG_B_;
    float*       ob = outp + (size_t)b * IMG_B_;

    #pragma unroll
    for (int i = 0; i < 4; ++i) {
        const int c = c0 + ty + i * 8;
        tile[ty + i * 8][tx] = ib[(size_t)c * PLANE_ + p0 + tx];
    }
    __syncthreads();
    #pragma unroll
    for (int i = 0; i < 4; ++i) {
        const int p = p0 + ty + i * 8;
        ob[(size_t)p * CI_ + c0 + tx] = tile[tx][ty + i * 8];
    }
}

// ---------------------------------------------------------------------------
// Main kernel: one wave (64 lanes) per point. Projection computed wave-
// uniformly (scalarized); each corner read is 256 contiguous floats =
// 64 lanes x float4, perfectly coalesced. Output row write coalesced.
// ---------------------------------------------------------------------------
__global__ __launch_bounds__(256) void i2p_main(
    const float* __restrict__ points_mean,  // (N,1,3)
    const float* __restrict__ voxel_feats,  // (N,64)
    const int*   __restrict__ coors,        // (N,4)
    const float* __restrict__ img_t,        // (B, P, C) transposed
    const float* __restrict__ lidar2img,    // (B,4,4)
    const int*   __restrict__ pad_shape,    // (B,2)
    float*       __restrict__ out,          // (N,320)
    int N)
{
    const int wid  = __builtin_amdgcn_readfirstlane(threadIdx.x >> 6); // wave in block
    const int lane = threadIdx.x & 63;
    const int n    = blockIdx.x * 4 + wid;
    if (n >= N) return;

    // ---- wave-uniform projection (scalar-cache loads, ~40 VALU ops) ----
    const int b  = coors[n * 4];
    const float px = points_mean[n * 3 + 0];
    const float py = points_mean[n * 3 + 1];
    const float pz = points_mean[n * 3 + 2];
    const float* M = lidar2img + b * 16;
    const float ip0 = M[0]*px + M[1]*py + M[2]*pz  + M[3];
    const float ip1 = M[4]*px + M[5]*py + M[6]*pz  + M[7];
    const float ip2 = M[8]*px + M[9]*py + M[10]*pz + M[11];
    const float z  = fmaxf(ip2, 1e-5f);
    const float x_pix = ip0 / z;
    const float y_pix = ip1 / z;
    const float hw0 = (float)pad_shape[b * 2 + 0];   // PAD_H
    const float hw1 = (float)pad_shape[b * 2 + 1];   // PAD_W
    const float gx = x_pix / hw1 * 2.0f - 1.0f;
    const float gy = y_pix / hw0 * 2.0f - 1.0f;
    const float ix = (gx + 1.0f) * 0.5f * (float)(WF_ - 1);
    const float iy = (gy + 1.0f) * 0.5f * (float)(HF_ - 1);
    const float ix0 = floorf(ix);
    const float iy0 = floorf(iy);
    const float wx1 = ix - ix0, wx0 = 1.0f - wx1;
    const float wy1 = iy - iy0, wy0 = 1.0f - wy1;

    const float xs[2]  = {ix0, ix0 + 1.0f};
    const float ys[2]  = {iy0, iy0 + 1.0f};
    const float wxs[2] = {wx0, wx1};
    const float wys[2] = {wy0, wy1};

    float w[4];
    size_t base[4];
    #pragma unroll
    for (int ky = 0; ky < 2; ++ky) {
        #pragma unroll
        for (int kx = 0; kx < 2; ++kx) {
            const int k = ky * 2 + kx;
            const bool valid =
                (ys[ky] >= 0.0f) && (ys[ky] <= (float)(HF_ - 1)) &&
                (xs[kx] >= 0.0f) && (xs[kx] <= (float)(WF_ - 1));
            if (valid) {
                const int yc = (int)ys[ky];
                const int xc = (int)xs[kx];
                base[k] = ((size_t)b * PLANE_ + yc * WF_ + xc) * CI_;
                w[k]    = wys[ky] * wxs[kx];
            } else {
                base[k] = 0;
                w[k]    = 0.0f;
            }
        }
    }

    // ---- voxel copy: 64 lanes x 1 float, coalesced 256 B ----
    out[(size_t)n * 320 + lane] = voxel_feats[(size_t)n * 64 + lane];

    // ---- bilinear gather: per corner 64 lanes x float4 = contiguous 1 KB ----
    float4 acc = make_float4(0.f, 0.f, 0.f, 0.f);
    #pragma unroll
    for (int k = 0; k < 4; ++k) {
        const float wk = w[k];           // wave-uniform -> uniform branch
        if (wk != 0.0f) {
            const float4 v = *reinterpret_cast<const float4*>(img_t + base[k] + lane * 4);
            acc.x += wk * v.x;
            acc.y += wk * v.y;
            acc.z += wk * v.z;
            acc.w += wk * v.w;
        }
    }
    *reinterpret_cast<float4*>(out + (size_t)n * 320 + 64 + lane * 4) = acc;
}

// ---------------------------------------------------------------------------
// Fallback (round-1 kernel) if workspace is too small for the transpose.
// ---------------------------------------------------------------------------
__global__ __launch_bounds__(320) void i2p_fallback(
    const float* __restrict__ points_mean,
    const float* __restrict__ voxel_feats,
    const int*   __restrict__ coors,
    const float* __restrict__ img_feats,
    const float* __restrict__ lidar2img,
    const int*   __restrict__ pad_shape,
    float*       __restrict__ out,
    int N)
{
    __shared__ float sw[4];
    __shared__ int   sb[4];
    const int n = blockIdx.x;
    if (n >= N) return;
    const int t = threadIdx.x;
    if (t == 0) {
        const int b = coors[n * 4];
        const float px = points_mean[n * 3 + 0];
        const float py = points_mean[n * 3 + 1];
        const float pz = points_mean[n * 3 + 2];
        const float* M = lidar2img + b * 16;
        const float ip0 = M[0]*px + M[1]*py + M[2]*pz  + M[3];
        const float ip1 = M[4]*px + M[5]*py + M[6]*pz  + M[7];
        const float ip2 = M[8]*px + M[9]*py + M[10]*pz + M[11];
        const float z  = fmaxf(ip2, 1e-5f);
        const float x_pix = ip0 / z;
        const float y_pix = ip1 / z;
        const float hw0 = (float)pad_shape[b * 2 + 0];
        const float hw1 = (float)pad_shape[b * 2 + 1];
        const float gx = x_pix / hw1 * 2.0f - 1.0f;
        const float gy = y_pix / hw0 * 2.0f - 1.0f;
        const float ix = (gx + 1.0f) * 0.5f * (float)(WF_ - 1);
        const float iy = (gy + 1.0f) * 0.5f * (float)(HF_ - 1);
        const float ix0 = floorf(ix);
        const float iy0 = floorf(iy);
        const float wx1 = ix - ix0, wx0 = 1.0f - wx1;
        const float wy1 = iy - iy0, wy0 = 1.0f - wy1;
        const float xs[2]  = {ix0, ix0 + 1.0f};
        const float ys[2]  = {iy0, iy0 + 1.0f};
        const float wxs[2] = {wx0, wx1};
        const float wys[2] = {wy0, wy1};
        const int ib = b * IMG_B_;
        #pragma unroll
        for (int ky = 0; ky < 2; ++ky)
            #pragma unroll
            for (int kx = 0; kx < 2; ++kx) {
                const int k = ky * 2 + kx;
                const bool valid =
                    (ys[ky] >= 0.0f) && (ys[ky] <= (float)(HF_ - 1)) &&
                    (xs[kx] >= 0.0f) && (xs[kx] <= (float)(WF_ - 1));
                if (valid) {
                    sb[k] = ib + (int)ys[ky] * WF_ + (int)xs[kx];
                    sw[k] = wys[ky] * wxs[kx];
                } else { sb[k] = 0; sw[k] = 0.0f; }
            }
    }
    __syncthreads();
    const long o = (long)n * 320 + t;
    if (t < 64) {
        out[o] = voxel_feats[(long)n * 64 + t];
    } else {
        const int c = t - 64;
        const int coff = c * PLANE_;
        float acc = 0.0f;
        #pragma unroll
        for (int k = 0; k < 4; ++k) {
            const float w = sw[k];
            if (w != 0.0f) acc += w * img_feats[sb[k] + coff];
        }
        out[o] = acc;
    }
}

extern "C" void kernel_launch(void* const* d_in, const int* in_sizes, int n_in,
                              void* d_out, int out_size, void* d_ws, size_t ws_size,
                              hipStream_t stream) {
    const float* points_mean = (const float*)d_in[0];
    // d_in[1] = mask (unused by forward)
    const float* voxel_feats = (const float*)d_in[2];
    const int*   coors       = (const int*)d_in[3];
    const float* img_feats   = (const float*)d_in[4];
    const float* lidar2img   = (const float*)d_in[5];
    const int*   pad_shape   = (const int*)d_in[6];
    float*       out         = (float*)d_out;

    const int N = in_sizes[0] / 3;   // points_mean is (N,1,3)

    if (ws_size >= IMG_BYTES_) {
        float* img_t = (float*)d_ws;
        dim3 tgrid(PLANE_ / 32, CI_ / 32, B_);   // 240 x 8 x 4
        hipLaunchKernelGGL(transpose_kernel, tgrid, dim3(256), 0, stream,
                           img_feats, img_t);
        dim3 grid((N + 3) / 4);
        hipLaunchKernelGGL(i2p_main, grid, dim3(256), 0, stream,
                           points_mean, voxel_feats, coors, img_t,
                           lidar2img, pad_shape, out, N);
    } else {
        hipLaunchKernelGGL(i2p_fallback, dim3(N), dim3(320), 0, stream,
                           points_mean, voxel_feats, coors, img_feats,
                           lidar2img, pad_shape, out, N);
    }
}

// Round 4
// 369.638 us; speedup vs baseline: 1.6136x; 1.0168x over previous
//
#include <hip/hip_runtime.h>
#include <hip/hip_fp16.h>

#define B_   4
#define CV_  64
#define CI_  256
#define HF_  48
#define WF_  160
#define PLANE_ (HF_*WF_)            // 7680
#define IMG_B_ (CI_*PLANE_)         // 1966080 elems per batch
#define IMG_T_BYTES_ ((size_t)B_ * IMG_B_ * 2)   // fp16: 15,728,640 B

// ---------------------------------------------------------------------------
// Pre-pass: transpose img_feats (B, C, P) f32 -> img_t (B, P, C) fp16.
// LDS-tiled 32x32; read coalesced 128B rows, write 64B fp16 rows.
// ---------------------------------------------------------------------------
__global__ __launch_bounds__(256) void transpose_h_kernel(
    const float* __restrict__ in,    // (B, C, P)
    __half*      __restrict__ outp)  // (B, P, C)
{
    __shared__ float tile[32][33];   // +1 pad: no bank conflicts
    const int b  = blockIdx.z;
    const int p0 = blockIdx.x * 32;  // pixel tile
    const int c0 = blockIdx.y * 32;  // channel tile
    const int tx = threadIdx.x & 31;
    const int ty = threadIdx.x >> 5; // 0..7

    const float* ib = in   + (size_t)b * IMG_B_;
    __half*      ob = outp + (size_t)b * IMG_B_;

    #pragma unroll
    for (int i = 0; i < 4; ++i) {
        const int c = c0 + ty + i * 8;
        tile[ty + i * 8][tx] = ib[(size_t)c * PLANE_ + p0 + tx];
    }
    __syncthreads();
    #pragma unroll
    for (int i = 0; i < 4; ++i) {
        const int p = p0 + ty + i * 8;
        ob[(size_t)p * CI_ + c0 + tx] = __float2half_rn(tile[tx][ty + i * 8]);
    }
}

// ---------------------------------------------------------------------------
// Main kernel: one wave (64 lanes) per point. Each lane owns 4 channels.
// Per corner: 64 lanes x 8 B (uint2 of 4 halves) = contiguous 512 B read,
// L2-resident (one batch slice = 3.93 MB fp16 < 4 MB XCD L2).
// Output + voxel streams are non-temporal so they don't evict the image.
// ---------------------------------------------------------------------------
__global__ __launch_bounds__(256) void i2p_main_h(
    const float*  __restrict__ points_mean,  // (N,1,3)
    const float*  __restrict__ voxel_feats,  // (N,64)
    const int*    __restrict__ coors,        // (N,4)
    const __half* __restrict__ img_t,        // (B, P, C) fp16
    const float*  __restrict__ lidar2img,    // (B,4,4)
    const int*    __restrict__ pad_shape,    // (B,2)
    float*        __restrict__ out,          // (N,320)
    int N)
{
    const int wid  = __builtin_amdgcn_readfirstlane(threadIdx.x >> 6);
    const int lane = threadIdx.x & 63;
    const int n    = blockIdx.x * 4 + wid;
    if (n >= N) return;

    // ---- wave-uniform projection ----
    const int b  = coors[n * 4];
    const float px = points_mean[n * 3 + 0];
    const float py = points_mean[n * 3 + 1];
    const float pz = points_mean[n * 3 + 2];
    const float* M = lidar2img + b * 16;
    const float ip0 = M[0]*px + M[1]*py + M[2]*pz  + M[3];
    const float ip1 = M[4]*px + M[5]*py + M[6]*pz  + M[7];
    const float ip2 = M[8]*px + M[9]*py + M[10]*pz + M[11];
    const float z  = fmaxf(ip2, 1e-5f);
    const float x_pix = ip0 / z;
    const float y_pix = ip1 / z;
    const float hw0 = (float)pad_shape[b * 2 + 0];   // PAD_H
    const float hw1 = (float)pad_shape[b * 2 + 1];   // PAD_W
    const float gx = x_pix / hw1 * 2.0f - 1.0f;
    const float gy = y_pix / hw0 * 2.0f - 1.0f;
    const float ix = (gx + 1.0f) * 0.5f * (float)(WF_ - 1);
    const float iy = (gy + 1.0f) * 0.5f * (float)(HF_ - 1);
    const float ix0 = floorf(ix);
    const float iy0 = floorf(iy);
    const float wx1 = ix - ix0, wx0 = 1.0f - wx1;
    const float wy1 = iy - iy0, wy0 = 1.0f - wy1;

    const float xs[2]  = {ix0, ix0 + 1.0f};
    const float ys[2]  = {iy0, iy0 + 1.0f};
    const float wxs[2] = {wx0, wx1};
    const float wys[2] = {wy0, wy1};

    float  w[4];
    size_t base[4];
    #pragma unroll
    for (int ky = 0; ky < 2; ++ky) {
        #pragma unroll
        for (int kx = 0; kx < 2; ++kx) {
            const int k = ky * 2 + kx;
            // validity on the FLOAT side (avoids out-of-range f->i UB)
            const bool valid =
                (ys[ky] >= 0.0f) && (ys[ky] <= (float)(HF_ - 1)) &&
                (xs[kx] >= 0.0f) && (xs[kx] <= (float)(WF_ - 1));
            if (valid) {
                const int yc = (int)ys[ky];
                const int xc = (int)xs[kx];
                base[k] = ((size_t)b * PLANE_ + yc * WF_ + xc) * CI_;
                w[k]    = wys[ky] * wxs[kx];
            } else {
                base[k] = 0;
                w[k]    = 0.0f;
            }
        }
    }

    // ---- voxel copy: 64 lanes x 1 float, coalesced 256 B (streaming) ----
    {
        const float v = __builtin_nontemporal_load(voxel_feats + (size_t)n * 64 + lane);
        __builtin_nontemporal_store(v, out + (size_t)n * 320 + lane);
    }

    // ---- bilinear gather: lane owns channels [lane*4, lane*4+4) ----
    float4 acc = make_float4(0.f, 0.f, 0.f, 0.f);
    #pragma unroll
    for (int k = 0; k < 4; ++k) {
        const float wk = w[k];              // wave-uniform -> uniform branch
        if (wk != 0.0f) {
            const uint2 u = *reinterpret_cast<const uint2*>(img_t + base[k] + lane * 4);
            const __half2 h01 = *reinterpret_cast<const __half2*>(&u.x);
            const __half2 h23 = *reinterpret_cast<const __half2*>(&u.y);
            const float2 f01 = __half22float2(h01);
            const float2 f23 = __half22float2(h23);
            acc.x += wk * f01.x;
            acc.y += wk * f01.y;
            acc.z += wk * f23.x;
            acc.w += wk * f23.y;
        }
    }
    // streaming 16B store, keep L2 for the image
    float* op = out + (size_t)n * 320 + 64 + lane * 4;
    __builtin_nontemporal_store(acc.x, op + 0);
    __builtin_nontemporal_store(acc.y, op + 1);
    __builtin_nontemporal_store(acc.z, op + 2);
    __builtin_nontemporal_store(acc.w, op + 3);
}

// ---------------------------------------------------------------------------
// Fallback (round-1 style, direct f32 layout) if workspace too small.
// ---------------------------------------------------------------------------
__global__ __launch_bounds__(320) void i2p_fallback(
    const float* __restrict__ points_mean,
    const float* __restrict__ voxel_feats,
    const int*   __restrict__ coors,
    const float* __restrict__ img_feats,
    const float* __restrict__ lidar2img,
    const int*   __restrict__ pad_shape,
    float*       __restrict__ out,
    int N)
{
    __shared__ float sw[4];
    __shared__ int   sb[4];
    const int n = blockIdx.x;
    if (n >= N) return;
    const int t = threadIdx.x;
    if (t == 0) {
        const int b = coors[n * 4];
        const float px = points_mean[n * 3 + 0];
        const float py = points_mean[n * 3 + 1];
        const float pz = points_mean[n * 3 + 2];
        const float* M = lidar2img + b * 16;
        const float ip0 = M[0]*px + M[1]*py + M[2]*pz  + M[3];
        const float ip1 = M[4]*px + M[5]*py + M[6]*pz  + M[7];
        const float ip2 = M[8]*px + M[9]*py + M[10]*pz + M[11];
        const float z  = fmaxf(ip2, 1e-5f);
        const float x_pix = ip0 / z;
        const float y_pix = ip1 / z;
        const float hw0 = (float)pad_shape[b * 2 + 0];
        const float hw1 = (float)pad_shape[b * 2 + 1];
        const float gx = x_pix / hw1 * 2.0f - 1.0f;
        const float gy = y_pix / hw0 * 2.0f - 1.0f;
        const float ix = (gx + 1.0f) * 0.5f * (float)(WF_ - 1);
        const float iy = (gy + 1.0f) * 0.5f * (float)(HF_ - 1);
        const float ix0 = floorf(ix);
        const float iy0 = floorf(iy);
        const float wx1 = ix - ix0, wx0 = 1.0f - wx1;
        const float wy1 = iy - iy0, wy0 = 1.0f - wy1;
        const float xs[2]  = {ix0, ix0 + 1.0f};
        const float ys[2]  = {iy0, iy0 + 1.0f};
        const float wxs[2] = {wx0, wx1};
        const float wys[2] = {wy0, wy1};
        const int ib = b * IMG_B_;
        #pragma unroll
        for (int ky = 0; ky < 2; ++ky)
            #pragma unroll
            for (int kx = 0; kx < 2; ++kx) {
                const int k = ky * 2 + kx;
                const bool valid =
                    (ys[ky] >= 0.0f) && (ys[ky] <= (float)(HF_ - 1)) &&
                    (xs[kx] >= 0.0f) && (xs[kx] <= (float)(WF_ - 1));
                if (valid) {
                    sb[k] = ib + (int)ys[ky] * WF_ + (int)xs[kx];
                    sw[k] = wys[ky] * wxs[kx];
                } else { sb[k] = 0; sw[k] = 0.0f; }
            }
    }
    __syncthreads();
    const long o = (long)n * 320 + t;
    if (t < 64) {
        out[o] = voxel_feats[(long)n * 64 + t];
    } else {
        const int c = t - 64;
        const int coff = c * PLANE_;
        float acc = 0.0f;
        #pragma unroll
        for (int k = 0; k < 4; ++k) {
            const float w = sw[k];
            if (w != 0.0f) acc += w * img_feats[sb[k] + coff];
        }
        out[o] = acc;
    }
}

extern "C" void kernel_launch(void* const* d_in, const int* in_sizes, int n_in,
                              void* d_out, int out_size, void* d_ws, size_t ws_size,
                              hipStream_t stream) {
    const float* points_mean = (const float*)d_in[0];
    // d_in[1] = mask (unused by forward)
    const float* voxel_feats = (const float*)d_in[2];
    const int*   coors       = (const int*)d_in[3];
    const float* img_feats   = (const float*)d_in[4];
    const float* lidar2img   = (const float*)d_in[5];
    const int*   pad_shape   = (const int*)d_in[6];
    float*       out         = (float*)d_out;

    const int N = in_sizes[0] / 3;   // points_mean is (N,1,3)

    if (ws_size >= IMG_T_BYTES_) {
        __half* img_t = (__half*)d_ws;
        dim3 tgrid(PLANE_ / 32, CI_ / 32, B_);   // 240 x 8 x 4
        hipLaunchKernelGGL(transpose_h_kernel, tgrid, dim3(256), 0, stream,
                           img_feats, img_t);
        dim3 grid((N + 3) / 4);
        hipLaunchKernelGGL(i2p_main_h, grid, dim3(256), 0, stream,
                           points_mean, voxel_feats, coors, img_t,
                           lidar2img, pad_shape, out, N);
    } else {
        hipLaunchKernelGGL(i2p_fallback, dim3(N), dim3(320), 0, stream,
                           points_mean, voxel_feats, coors, img_feats,
                           lidar2img, pad_shape, out, N);
    }
}